// Round 1
// baseline (69.701 us; speedup 1.0000x reference)
//
#include <hip/hip_runtime.h>

// Blocksparse Deep ReLU GAM forward.
// 128 towers, each 2->16->12->8->1 MLP over selected input pair (2j, 2j+1),
// outputs summed per sample + scalar bias. shape_loss output = zeros(128).

constexpr int BATCH = 32768;
constexpr int FEAT  = 256;
constexpr int NTOW  = 128;
constexpr int TPT   = 368;                 // padded floats per tower (365 used)
constexpr int TOW_PER_BLK = 32;
constexpr int SLAB  = TOW_PER_BLK * TPT;   // 11776 floats = 47.1 KB LDS

// Pack offsets within a tower record:
//  [0,32)    w0  (r-major pairs: w0[2r]=W0[16t+r,2t], w0[2r+1]=W0[16t+r,2t+1])
//  [32,48)   b0
//  [48,240)  w1  (12 rows x 16)
//  [240,252) b1
//  [252,348) w2  (8 rows x 12)
//  [348,356) b2
//  [356,364) w3  (8)
//  [364]     b3
//  [365,368) pad

__device__ __forceinline__ float gather_weight(
    int t, int i,
    const float* __restrict__ W0, const float* __restrict__ B0,
    const float* __restrict__ W1, const float* __restrict__ B1,
    const float* __restrict__ W2, const float* __restrict__ B2,
    const float* __restrict__ W3, const float* __restrict__ B3) {
  float v = 0.f;
  if (i < 32)       { int r = i >> 1, c = i & 1;               v = W0[(16*t + r)*FEAT + 2*t + c]; }
  else if (i < 48)  {                                           v = B0[16*t + (i - 32)]; }
  else if (i < 240) { int k = i - 48, r = k >> 4, c = k & 15;   v = W1[(12*t + r)*(16*NTOW) + 16*t + c]; }
  else if (i < 252) {                                           v = B1[12*t + (i - 240)]; }
  else if (i < 348) { int k = i - 252, r = k / 12, c = k - 12*r; v = W2[(8*t + r)*(12*NTOW) + 12*t + c]; }
  else if (i < 356) {                                           v = B2[8*t + (i - 348)]; }
  else if (i < 364) {                                           v = W3[t*(8*NTOW) + 8*t + (i - 356)]; }
  else if (i == 364){                                           v = B3[t]; }
  return v;
}

__global__ void pack_weights(
    const float* __restrict__ W0, const float* __restrict__ B0,
    const float* __restrict__ W1, const float* __restrict__ B1,
    const float* __restrict__ W2, const float* __restrict__ B2,
    const float* __restrict__ W3, const float* __restrict__ B3,
    float* __restrict__ pack) {
  const int t = blockIdx.x;
  for (int i = threadIdx.x; i < TPT; i += blockDim.x)
    pack[t * TPT + i] = gather_weight(t, i, W0, B0, W1, B1, W2, B2, W3, B3);
}

template <bool PACKED>
__global__ __launch_bounds__(256, 2) void bs_fwd(
    const float* __restrict__ x,
    const float* __restrict__ pack,
    const float* __restrict__ W0, const float* __restrict__ B0,
    const float* __restrict__ W1, const float* __restrict__ B1,
    const float* __restrict__ W2, const float* __restrict__ B2,
    const float* __restrict__ W3, const float* __restrict__ B3,
    const float* __restrict__ bias,
    float* __restrict__ out) {
  __shared__ float w[SLAB];
  const int g    = blockIdx.x & 3;    // tower group: towers [32g, 32g+32)
  const int tile = blockIdx.x >> 2;   // sample tile: samples [256*tile, 256*tile+256)

  if (PACKED) {
    const float4* __restrict__ src = (const float4*)(pack + (size_t)g * SLAB);
    float4* dst = (float4*)w;
    for (int i = threadIdx.x; i < SLAB / 4; i += 256) dst[i] = src[i];
  } else {
    for (int i = threadIdx.x; i < SLAB; i += 256) {
      const int tl  = i / TPT;
      const int idx = i - tl * TPT;
      w[i] = gather_weight(g * TOW_PER_BLK + tl, idx, W0, B0, W1, B1, W2, B2, W3, B3);
    }
  }
  __syncthreads();

  const int s = tile * 256 + threadIdx.x;
  const float* __restrict__ xrow = x + (size_t)s * FEAT + g * 64;

  float acc = (g == 0) ? bias[0] : 0.f;
  float2 xp = *(const float2*)(xrow);

  for (int t = 0; t < TOW_PER_BLK; ++t) {
    const float2 xn = (t < TOW_PER_BLK - 1) ? *(const float2*)(xrow + 2 * t + 2) : xp;
    const float* __restrict__ tw = w + t * TPT;

    float h0[16];
#pragma unroll
    for (int r = 0; r < 16; ++r)
      h0[r] = fmaxf(0.f, fmaf(tw[2*r], xp.x, fmaf(tw[2*r + 1], xp.y, tw[32 + r])));

    float h1[12];
#pragma unroll
    for (int r = 0; r < 12; ++r) {
      float sum = tw[240 + r];
#pragma unroll
      for (int c = 0; c < 16; ++c) sum = fmaf(tw[48 + 16*r + c], h0[c], sum);
      h1[r] = fmaxf(0.f, sum);
    }

    float h2[8];
#pragma unroll
    for (int r = 0; r < 8; ++r) {
      float sum = tw[348 + r];
#pragma unroll
      for (int c = 0; c < 12; ++c) sum = fmaf(tw[252 + 12*r + c], h1[c], sum);
      h2[r] = fmaxf(0.f, sum);
    }

    float sum = tw[364];
#pragma unroll
    for (int c = 0; c < 8; ++c) sum = fmaf(tw[356 + c], h2[c], sum);
    acc += sum;

    xp = xn;
  }

  atomicAdd(out + s, acc);
}

extern "C" void kernel_launch(void* const* d_in, const int* in_sizes, int n_in,
                              void* d_out, int out_size, void* d_ws, size_t ws_size,
                              hipStream_t stream) {
  const float* x    = (const float*)d_in[0];
  const float* W0   = (const float*)d_in[1];
  const float* B0   = (const float*)d_in[2];
  const float* W1   = (const float*)d_in[3];
  const float* B1   = (const float*)d_in[4];
  const float* W2   = (const float*)d_in[5];
  const float* B2   = (const float*)d_in[6];
  const float* W3   = (const float*)d_in[7];
  const float* B3   = (const float*)d_in[8];
  const float* bias = (const float*)d_in[9];
  float* out = (float*)d_out;

  // Zero outputs: out[0:32768] accumulated via atomics, shape_loss[128] stays 0.
  hipMemsetAsync(d_out, 0, (size_t)out_size * sizeof(float), stream);

  const size_t packBytes = (size_t)NTOW * TPT * sizeof(float);
  const int grid = (BATCH / 256) * (NTOW / TOW_PER_BLK);  // 512 blocks

  if (ws_size >= packBytes) {
    float* pack = (float*)d_ws;
    pack_weights<<<NTOW, 128, 0, stream>>>(W0, B0, W1, B1, W2, B2, W3, B3, pack);
    bs_fwd<true><<<grid, 256, 0, stream>>>(x, pack, W0, B0, W1, B1, W2, B2, W3, B3, bias, out);
  } else {
    bs_fwd<false><<<grid, 256, 0, stream>>>(x, nullptr, W0, B0, W1, B1, W2, B2, W3, B3, bias, out);
  }
}